// Round 1
// baseline (2648.020 us; speedup 1.0000x reference)
//
#include <hip/hip_runtime.h>
#include <hip/hip_bf16.h>

#define T_STEPS 512
#define BATCH   256

__device__ __forceinline__ float sigmoid_f(float x) {
    return 1.0f / (1.0f + __expf(-x));
}
__device__ __forceinline__ float tanh_f(float x) {
    // 1 - 2/(e^{2x}+1): no NaN for large |x| (inf -> 1, 0 -> -1)
    return 1.0f - 2.0f / (__expf(2.0f * x) + 1.0f);
}

// One block per batch element. Thread j in [0, 4H) owns gate-output j.
// w_ih[j,:] and w_hh[j,:] live in registers. x_t / h / g go through LDS.
template <int IN_DIM, int H, bool APPLY_TANH>
__global__ __launch_bounds__(4 * H, (H >= 64 ? H / 64 : 1))
void lstm_layer(const float* __restrict__ x,      // [T, B, IN_DIM]
                const float* __restrict__ w_ih,   // [4H, IN_DIM]
                const float* __restrict__ w_hh,   // [4H, H]
                const float* __restrict__ b_ih,   // [4H]
                const float* __restrict__ b_hh,   // [4H]
                float* __restrict__ out)          // [T, B, H]
{
    constexpr int G = 4 * H;
    const int b = blockIdx.x;
    const int j = threadIdx.x;   // gate-output index

    __shared__ float xbuf[IN_DIM];
    __shared__ float hbuf[H];
    __shared__ float gbuf[G];

    // ---- load this thread's weight rows into registers (one-time) ----
    float wi[IN_DIM];
    float wh[H];
    {
        const float4* wip = (const float4*)(w_ih + (size_t)j * IN_DIM);
#pragma unroll
        for (int i = 0; i < IN_DIM / 4; ++i) {
            float4 v = wip[i];
            wi[4 * i + 0] = v.x; wi[4 * i + 1] = v.y;
            wi[4 * i + 2] = v.z; wi[4 * i + 3] = v.w;
        }
        const float4* whp = (const float4*)(w_hh + (size_t)j * H);
#pragma unroll
        for (int k = 0; k < H / 4; ++k) {
            float4 v = whp[k];
            wh[4 * k + 0] = v.x; wh[4 * k + 1] = v.y;
            wh[4 * k + 2] = v.z; wh[4 * k + 3] = v.w;
        }
    }
    const float bias = b_ih[j] + b_hh[j];

    float c = 0.0f;
    if (j < H) hbuf[j] = 0.0f;

    const float* xrow = x + (size_t)b * IN_DIM;   // + t*B*IN_DIM
    float xpre = (j < IN_DIM) ? xrow[j] : 0.0f;   // prefetch t=0

    for (int t = 0; t < T_STEPS; ++t) {
        if (j < IN_DIM) xbuf[j] = xpre;
        __syncthreads();   // xbuf + hbuf(t-1) visible

        // prefetch next timestep's x while we compute
        if (j < IN_DIM && t + 1 < T_STEPS)
            xpre = xrow[(size_t)(t + 1) * BATCH * IN_DIM + j];

        float g = bias;
#pragma unroll
        for (int i = 0; i < IN_DIM; ++i) g += xbuf[i] * wi[i];
#pragma unroll
        for (int k = 0; k < H; ++k) g += hbuf[k] * wh[k];
        gbuf[j] = g;
        __syncthreads();   // gbuf complete; all readers of hbuf/xbuf done

        if (j < H) {
            float gi = gbuf[j];
            float gf = gbuf[H + j];
            float gg = gbuf[2 * H + j];
            float go = gbuf[3 * H + j];
            c = sigmoid_f(gf) * c + sigmoid_f(gi) * tanh_f(gg);
            float h = sigmoid_f(go) * tanh_f(c);
            hbuf[j] = h;   // visible at next iteration's first sync
            out[((size_t)t * BATCH + b) * H + j] = APPLY_TANH ? tanh_f(h) : h;
        }
    }
}

extern "C" void kernel_launch(void* const* d_in, const int* in_sizes, int n_in,
                              void* d_out, int out_size, void* d_ws, size_t ws_size,
                              hipStream_t stream) {
    const float* X     = (const float*)d_in[0];
    const float* w1_ih = (const float*)d_in[1];
    const float* w1_hh = (const float*)d_in[2];
    const float* b1_ih = (const float*)d_in[3];
    const float* b1_hh = (const float*)d_in[4];
    const float* w2_ih = (const float*)d_in[5];
    const float* w2_hh = (const float*)d_in[6];
    const float* b2_ih = (const float*)d_in[7];
    const float* b2_hh = (const float*)d_in[8];
    const float* w3_ih = (const float*)d_in[9];
    const float* w3_hh = (const float*)d_in[10];
    const float* b3_ih = (const float*)d_in[11];
    const float* b3_hh = (const float*)d_in[12];
    const float* w4_ih = (const float*)d_in[13];
    const float* w4_hh = (const float*)d_in[14];
    const float* b4_ih = (const float*)d_in[15];
    const float* b4_hh = (const float*)d_in[16];

    float* out = (float*)d_out;

    // workspace: h1 [512,256,128] fp32, h2 [512,256,32] fp32; h3 reuses h1
    float* h1 = (float*)d_ws;
    float* h2 = h1 + (size_t)T_STEPS * BATCH * 128;

    // layer 1: 64 -> 128
    lstm_layer<64, 128, false><<<BATCH, 512, 0, stream>>>(X, w1_ih, w1_hh, b1_ih, b1_hh, h1);
    // layer 2: 128 -> 32, bottleneck tanh fused into output write
    lstm_layer<128, 32, true><<<BATCH, 128, 0, stream>>>(h1, w2_ih, w2_hh, b2_ih, b2_hh, h2);
    // layer 3: 32 -> 128 (reuse h1's space for h3)
    lstm_layer<32, 128, false><<<BATCH, 512, 0, stream>>>(h2, w3_ih, w3_hh, b3_ih, b3_hh, h1);
    // layer 4: 128 -> 64 -> d_out
    lstm_layer<128, 64, false><<<BATCH, 256, 0, stream>>>(h1, w4_ih, w4_hh, b4_ih, b4_hh, out);
}